// Round 1
// baseline (606.861 us; speedup 1.0000x reference)
//
#include <hip/hip_runtime.h>

// AttentionRNN: B=64, NUM=8, TC=64, H=128. bn=512 independent sequences.
// One block (256 thr) handles 2 sequences for the full 64-step scan.
// uproj kept in registers (64/thread); GRU weights streamed from L2 each step.

#define OFF_U     0      // [64][64] att_u staging (prologue only)
#define OFF_XMRM  4096   // [mat][seq][384] = [2][2][384]
#define OFF_HST   5632   // [2][128]
#define OFF_HPP   5888   // [2][4][64]  h_part partials
#define OFF_HPART 6400   // [2][64]
#define OFF_XTV   6528   // [2][128]  x_t = a * x_col
#define OFF_VV    6784   // [64] att_v
#define OFF_RED   6848   // [16] softmax cross-wave scratch
#define LDS_FLOATS 6864

__global__ __launch_bounds__(256, 1)
void attn_gru_kernel(const float* __restrict__ x, const float* __restrict__ att_v,
                     const float* __restrict__ att_w, const float* __restrict__ att_u,
                     const float* __restrict__ gk, const float* __restrict__ grk,
                     const float* __restrict__ gbias, float* __restrict__ out) {
    __shared__ float lds[LDS_FLOATS];
    const int tid = threadIdx.x;
    const int bn0 = blockIdx.x * 2;

    // stage U, v; init h = 0
    for (int i = tid; i < 4096; i += 256) lds[OFF_U + i] = att_u[i];
    if (tid < 64) lds[OFF_VV + tid] = att_v[tid];
    lds[OFF_HST + tid] = 0.0f;
    __syncthreads();

    const int seq = tid >> 7;   // 0/1 : which of the block's 2 sequences
    const int hh  = tid & 127;  // feature index
    const int s_  = tid & 63;
    const int hg  = tid >> 6;   // 0..3 (also wave id)

    // per-thread uproj[seq][hh][0..63] in registers:
    //   uproj[hh][s] = sum_t x[bn, t, hh] * U[t, s]
    float upreg[64];
    #pragma unroll
    for (int s2 = 0; s2 < 64; ++s2) upreg[s2] = 0.0f;
    {
        const float* xb = x + (size_t)(bn0 + seq) * 8192 + hh;
        for (int t = 0; t < 64; ++t) {
            float xv = xb[t * 128];                  // coalesced across hh lanes
            const float* Ur = lds + OFF_U + t * 64;  // broadcast reads
            #pragma unroll
            for (int s2 = 0; s2 < 64; ++s2) upreg[s2] += xv * Ur[s2];
        }
    }

    // att_w in registers: thread (hg, s_) owns W[hg*32+k][s_], k=0..31
    float wreg[32];
    #pragma unroll
    for (int k = 0; k < 32; ++k) wreg[k] = att_w[(hg * 32 + k) * 64 + s_];

    // GRU matvec (phase D) per-thread constants: quad of weight columns
    const int col4 = tid * 4;                 // 0..764 for tid<192
    const int dmat = (col4 >= 384) ? 1 : 0;   // 0 -> gru_kernel (input x_t), 1 -> gru_rkernel (input h)
    const int dj   = col4 - dmat * 384;       // multiple of 4
    const float* Wm = (dmat ? grk : gk) + dj;
    const int ivoff = dmat ? OFF_HST : OFF_XTV;
    float4 dbias = make_float4(0.f, 0.f, 0.f, 0.f);
    if (tid < 192) dbias = *(const float4*)(gbias + dmat * 384 + dj);

    __syncthreads();

    for (int t = 0; t < 64; ++t) {
        // ---- A: h_part partials: h_part[s] = sum_h h[h] * W[h][s]
        {
            float p0 = 0.f, p1 = 0.f;
            #pragma unroll
            for (int k = 0; k < 32; ++k) {
                float w = wreg[k];
                p0 += lds[OFF_HST + hg * 32 + k] * w;        // broadcast
                p1 += lds[OFF_HST + 128 + hg * 32 + k] * w;
            }
            lds[OFF_HPP + (0 * 4 + hg) * 64 + s_] = p0;
            lds[OFF_HPP + (1 * 4 + hg) * 64 + s_] = p1;
        }
        __syncthreads();
        // ---- B: reduce 4 row-group partials
        if (tid < 128) {
            int sq = tid >> 6, ss = tid & 63;
            lds[OFF_HPART + sq * 64 + ss] =
                  lds[OFF_HPP + (sq * 4 + 0) * 64 + ss]
                + lds[OFF_HPP + (sq * 4 + 1) * 64 + ss]
                + lds[OFF_HPP + (sq * 4 + 2) * 64 + ss]
                + lds[OFF_HPP + (sq * 4 + 3) * 64 + ss];
        }
        __syncthreads();
        // ---- C: e[hh] = sum_s tanh(h_part[s] + uproj[hh][s]) * v[s]; softmax over hh
        float e = 0.f;
        {
            const float* hp = lds + OFF_HPART + seq * 64;
            #pragma unroll
            for (int s2 = 0; s2 < 64; ++s2) {
                float arg = hp[s2] + upreg[s2];
                float u2 = __expf(2.0f * arg);                   // tanh = 1 - 2/(e^{2x}+1)
                float th = 1.0f - __fdividef(2.0f, u2 + 1.0f);   // saturates correctly at +/-1
                e += th * lds[OFF_VV + s2];
            }
        }
        float m = e;
        #pragma unroll
        for (int off = 32; off >= 1; off >>= 1) m = fmaxf(m, __shfl_xor(m, off, 64));
        if ((tid & 63) == 0) lds[OFF_RED + hg] = m;
        __syncthreads();
        m = fmaxf(lds[OFF_RED + seq * 2], lds[OFF_RED + seq * 2 + 1]);
        float p = __expf(e - m);
        float sm = p;
        #pragma unroll
        for (int off = 32; off >= 1; off >>= 1) sm += __shfl_xor(sm, off, 64);
        if ((tid & 63) == 0) lds[OFF_RED + 8 + hg] = sm;
        __syncthreads();
        float denom = lds[OFF_RED + 8 + seq * 2] + lds[OFF_RED + 8 + seq * 2 + 1];
        float a = __fdividef(p, denom);
        float xv = x[(size_t)(bn0 + seq) * 8192 + t * 128 + hh];  // x_col, read once ever
        lds[OFF_XTV + seq * 128 + hh] = a * xv;
        __syncthreads();
        // ---- D: xm = x_t@K + b_in ; rm = h@R + b_rec. 192 threads x 4 adjacent cols.
        if (tid < 192) {
            float4 a0 = make_float4(0.f, 0.f, 0.f, 0.f);
            float4 a1 = make_float4(0.f, 0.f, 0.f, 0.f);
            #pragma unroll 4
            for (int h = 0; h < 128; ++h) {
                const float4 w = *(const float4*)(Wm + h * 384);  // 16B/lane coalesced from L2
                float i0 = lds[ivoff + h];
                float i1 = lds[ivoff + 128 + h];
                a0.x += w.x * i0; a0.y += w.y * i0; a0.z += w.z * i0; a0.w += w.w * i0;
                a1.x += w.x * i1; a1.y += w.y * i1; a1.z += w.z * i1; a1.w += w.w * i1;
            }
            *(float4*)(lds + OFF_XMRM + (dmat * 2 + 0) * 384 + dj) =
                make_float4(a0.x + dbias.x, a0.y + dbias.y, a0.z + dbias.z, a0.w + dbias.w);
            *(float4*)(lds + OFF_XMRM + (dmat * 2 + 1) * 384 + dj) =
                make_float4(a1.x + dbias.x, a1.y + dbias.y, a1.z + dbias.z, a1.w + dbias.w);
        }
        __syncthreads();
        // ---- E: gates
        {
            const float* xm = lds + OFF_XMRM + (0 * 2 + seq) * 384;
            const float* rm = lds + OFF_XMRM + (1 * 2 + seq) * 384;
            float xz = xm[hh], xr = xm[128 + hh], xh = xm[256 + hh];
            float rz = rm[hh], rr = rm[128 + hh], rh = rm[256 + hh];
            float z = __fdividef(1.0f, 1.0f + __expf(-(xz + rz)));
            float r = __fdividef(1.0f, 1.0f + __expf(-(xr + rr)));
            float hc = xh + r * rh;
            hc = hc > 0.f ? hc : 0.f;
            float hold = lds[OFF_HST + seq * 128 + hh];
            lds[OFF_HST + seq * 128 + hh] = z * hold + (1.0f - z) * hc;
        }
        __syncthreads();
    }

    out[(size_t)(bn0 + seq) * 128 + hh] = lds[OFF_HST + seq * 128 + hh];
}

extern "C" void kernel_launch(void* const* d_in, const int* in_sizes, int n_in,
                              void* d_out, int out_size, void* d_ws, size_t ws_size,
                              hipStream_t stream) {
    (void)in_sizes; (void)n_in; (void)out_size; (void)d_ws; (void)ws_size;
    const float* x      = (const float*)d_in[0];
    const float* att_v  = (const float*)d_in[1];
    const float* att_w  = (const float*)d_in[2];
    const float* att_u  = (const float*)d_in[3];
    const float* gk     = (const float*)d_in[4];
    const float* grk    = (const float*)d_in[5];
    const float* gbias  = (const float*)d_in[6];
    float* out = (float*)d_out;
    hipLaunchKernelGGL(attn_gru_kernel, dim3(256), dim3(256), 0, stream,
                       x, att_v, att_w, att_u, gk, grk, gbias, out);
}